// Round 4
// baseline (24.146 us; speedup 1.0000x reference)
//
#include <hip/hip_runtime.h>

#define EPS 1e-6f

using f4 = __attribute__((ext_vector_type(4))) float;

// Wave-per-row fused RMSNorm + weighted-dot, max-occupancy variant:
// 8192 waves (one per row), 2048 blocks = 8 blocks/CU, VGPR capped to 64
// via __launch_bounds__(256,8) -> 32 waves/CU for maximal outstanding
// HBM requests. gamma/w re-read per wave but L1-resident (16 KB < 32 KB L1).
template<int D>
__global__ __launch_bounds__(256, 8) void lo_kernel(
    const float* __restrict__ enc,
    const float* __restrict__ gamma,
    const float* __restrict__ w,
    const float* __restrict__ bias,
    float* __restrict__ out,
    int N_IMG, int S, int n_rows)
{
    constexpr int ITER = D / 256;           // 64 lanes * 4 floats per iter
    const int lane = threadIdx.x & 63;
    const int row  = blockIdx.x * 4 + (threadIdx.x >> 6);
    if (row >= n_rows) return;

    const int b = row / N_IMG;
    const int n = row - b * N_IMG;
    const float* __restrict__ x = enc + ((size_t)b * S + n) * (size_t)D;
    const int col = lane * 4;

    f4 sq = {0.f, 0.f, 0.f, 0.f};
    f4 dt = {0.f, 0.f, 0.f, 0.f};
    #pragma unroll
    for (int i = 0; i < ITER; ++i) {
        const int idx = i * 256 + col;
        const f4 xv = __builtin_nontemporal_load(
            reinterpret_cast<const f4*>(x + idx));
        const f4 gv = *reinterpret_cast<const f4*>(gamma + idx);
        const f4 wv = *reinterpret_cast<const f4*>(w + idx);
        sq += xv * xv;
        dt += xv * (gv * wv);
    }

    float ssq = sq.x + sq.y + sq.z + sq.w;
    float ddt = dt.x + dt.y + dt.z + dt.w;
    #pragma unroll
    for (int o = 32; o > 0; o >>= 1) {
        ssq += __shfl_xor(ssq, o, 64);
        ddt += __shfl_xor(ddt, o, 64);
    }
    if (lane == 0) {
        out[row] = ddt * rsqrtf(ssq * (1.0f / (float)D) + EPS) + bias[0];
    }
}

// Generic fallback (runtime D), block-per-row.
__global__ __launch_bounds__(256) void lo_kernel_generic(
    const float* __restrict__ enc,
    const float* __restrict__ gamma,
    const float* __restrict__ w,
    const float* __restrict__ bias,
    float* __restrict__ out,
    int N_IMG, int S, int D)
{
    const int row = blockIdx.x;
    const int b   = row / N_IMG;
    const int n   = row % N_IMG;
    const float* __restrict__ x = enc + ((size_t)b * S + n) * (size_t)D;
    const int t = threadIdx.x;

    float sumsq = 0.f, dot = 0.f;
    for (int d = t; d < D; d += 256) {
        const float xv = x[d];
        sumsq = fmaf(xv, xv, sumsq);
        dot   = fmaf(xv * gamma[d], w[d], dot);
    }
    #pragma unroll
    for (int o = 32; o > 0; o >>= 1) {
        sumsq += __shfl_xor(sumsq, o, 64);
        dot   += __shfl_xor(dot,   o, 64);
    }
    __shared__ float s_sq[4], s_dot[4];
    const int wid = t >> 6, lane = t & 63;
    if (lane == 0) { s_sq[wid] = sumsq; s_dot[wid] = dot; }
    __syncthreads();
    if (t == 0) {
        float ss = s_sq[0] + s_sq[1] + s_sq[2] + s_sq[3];
        float dd = s_dot[0] + s_dot[1] + s_dot[2] + s_dot[3];
        out[row] = dd * rsqrtf(ss / (float)D + EPS) + bias[0];
    }
}

extern "C" void kernel_launch(void* const* d_in, const int* in_sizes, int n_in,
                              void* d_out, int out_size, void* d_ws, size_t ws_size,
                              hipStream_t stream) {
    const float* enc   = (const float*)d_in[0];   // (B, S, D)
    const float* gamma = (const float*)d_in[3];   // (D,)
    const float* w     = (const float*)d_in[4];   // (D,)
    const float* bias  = (const float*)d_in[5];   // scalar
    float* out         = (float*)d_out;           // (B, N_IMG)

    const int D      = in_sizes[3];               // 2048
    const int B      = 4;
    const int BN     = in_sizes[1];               // B * N_IMG
    const int N_IMG  = BN / B;
    const int S      = in_sizes[0] / (B * D);
    const int n_rows = out_size;                  // B * N_IMG = 8192

    if (D == 2048) {
        const int blocks = (n_rows + 3) / 4;      // wave-per-row: 2048 blocks
        lo_kernel<2048><<<blocks, 256, 0, stream>>>(enc, gamma, w, bias, out,
                                                    N_IMG, S, n_rows);
    } else {
        lo_kernel_generic<<<n_rows, 256, 0, stream>>>(enc, gamma, w, bias, out,
                                                      N_IMG, S, D);
    }
}

// Round 5
// 17.771 us; speedup vs baseline: 1.3587x; 1.3587x over previous
//
#include <hip/hip_runtime.h>

#define EPS 1e-6f

using f4 = __attribute__((ext_vector_type(4))) float;

// Grid-synchronous sequential-sweep kernel.
// 1024 blocks x 512 threads. "Iteration" i: block bid fully covers row
// R = i*nblk + bid (8 waves x 1KB chunks), so the whole grid reads one
// contiguous ~8MB window at a time -> the exact access pattern of the
// 6.3 TB/s copy microbenchmark. All 8 row-loads per thread are issued
// up-front (no barriers between), one __syncthreads at the end for the
// cross-wave combine.
template<int D, int NLOG2>   // D=2048, N_IMG = 1<<NLOG2 = 2048
__global__ __launch_bounds__(512, 4) void lo_sweep(
    const float* __restrict__ enc,
    const float* __restrict__ gamma,
    const float* __restrict__ wgt,
    const float* __restrict__ bias,
    float* __restrict__ out)
{
    const int tid  = threadIdx.x;
    const int wv_i = tid >> 6;            // wave 0..7
    const int lane = tid & 63;
    const int bid  = blockIdx.x;
    const int nblk = gridDim.x;           // n_rows / 8
    const int col  = wv_i * 256 + lane * 4;   // wave-fixed column slice

    // gamma*w for this thread's 4 columns, loaded once (L2-resident).
    const f4 gv = *reinterpret_cast<const f4*>(gamma + col);
    const f4 vv = *reinterpret_cast<const f4*>(wgt + col);
    const f4 gw = gv * vv;

    // Precompute the 8 row base addresses (S stride via 64-bit math).
    const float* xs[8];
    #pragma unroll
    for (int i = 0; i < 8; ++i) {
        const int R = i * nblk + bid;
        const int b = R >> NLOG2;               // batch
        const int n = R & ((1 << NLOG2) - 1);   // row within batch
        // S passed implicitly: enc row pitch within batch is D; batch
        // pitch is S*D — fold it via the precomputed table below.
        xs[i] = enc + ((size_t)b * 4096 /*S*/ + n) * (size_t)D + col;
    }

    // Issue all 8 loads back-to-back (deep pipeline, no barriers).
    f4 xv[8];
    #pragma unroll
    for (int i = 0; i < 8; ++i)
        xv[i] = __builtin_nontemporal_load(reinterpret_cast<const f4*>(xs[i]));

    float sq[8], dt[8];
    #pragma unroll
    for (int i = 0; i < 8; ++i) {
        const f4 s = xv[i] * xv[i];
        const f4 d = xv[i] * gw;
        sq[i] = s.x + s.y + s.z + s.w;
        dt[i] = d.x + d.y + d.z + d.w;
    }

    // Per-wave butterfly for each of the 8 row-chunks, partials -> LDS.
    __shared__ float part[8][8][2];   // [wave][iter][sq,dot]
    #pragma unroll
    for (int i = 0; i < 8; ++i) {
        float a = sq[i], c = dt[i];
        #pragma unroll
        for (int o = 32; o > 0; o >>= 1) {
            a += __shfl_xor(a, o, 64);
            c += __shfl_xor(c, o, 64);
        }
        if (lane == 0) { part[wv_i][i][0] = a; part[wv_i][i][1] = c; }
    }
    __syncthreads();

    // Finalize: wave w combines the 8 wave-partials of iter j=w
    // (row w*nblk + bid) using lanes 0..7.
    float a = 0.f, c = 0.f;
    if (lane < 8) { a = part[lane][wv_i][0]; c = part[lane][wv_i][1]; }
    #pragma unroll
    for (int o = 4; o > 0; o >>= 1) {
        a += __shfl_xor(a, o, 64);
        c += __shfl_xor(c, o, 64);
    }
    if (lane == 0) {
        const int R = wv_i * nblk + bid;
        out[R] = c * rsqrtf(a * (1.0f / (float)D) + EPS) + bias[0];
    }
}

// Generic fallback (runtime shapes), block-per-row.
__global__ __launch_bounds__(256) void lo_kernel_generic(
    const float* __restrict__ enc,
    const float* __restrict__ gamma,
    const float* __restrict__ w,
    const float* __restrict__ bias,
    float* __restrict__ out,
    int N_IMG, int S, int D)
{
    const int row = blockIdx.x;
    const int b   = row / N_IMG;
    const int n   = row % N_IMG;
    const float* __restrict__ x = enc + ((size_t)b * S + n) * (size_t)D;
    const int t = threadIdx.x;

    float sumsq = 0.f, dot = 0.f;
    for (int d = t; d < D; d += 256) {
        const float xv = x[d];
        sumsq = fmaf(xv, xv, sumsq);
        dot   = fmaf(xv * gamma[d], w[d], dot);
    }
    #pragma unroll
    for (int o = 32; o > 0; o >>= 1) {
        sumsq += __shfl_xor(sumsq, o, 64);
        dot   += __shfl_xor(dot,   o, 64);
    }
    __shared__ float s_sq[4], s_dot[4];
    const int wid = t >> 6, lane = t & 63;
    if (lane == 0) { s_sq[wid] = sumsq; s_dot[wid] = dot; }
    __syncthreads();
    if (t == 0) {
        float ss = s_sq[0] + s_sq[1] + s_sq[2] + s_sq[3];
        float dd = s_dot[0] + s_dot[1] + s_dot[2] + s_dot[3];
        out[row] = dd * rsqrtf(ss / (float)D + EPS) + bias[0];
    }
}

extern "C" void kernel_launch(void* const* d_in, const int* in_sizes, int n_in,
                              void* d_out, int out_size, void* d_ws, size_t ws_size,
                              hipStream_t stream) {
    const float* enc   = (const float*)d_in[0];   // (B, S, D)
    const float* gamma = (const float*)d_in[3];   // (D,)
    const float* w     = (const float*)d_in[4];   // (D,)
    const float* bias  = (const float*)d_in[5];   // scalar
    float* out         = (float*)d_out;           // (B, N_IMG)

    const int D      = in_sizes[3];               // 2048
    const int B      = 4;
    const int BN     = in_sizes[1];               // B * N_IMG
    const int N_IMG  = BN / B;
    const int S      = in_sizes[0] / (B * D);
    const int n_rows = out_size;                  // 8192

    if (D == 2048 && N_IMG == 2048 && S == 4096 && n_rows % 8 == 0) {
        const int nblk = n_rows / 8;              // 1024
        lo_sweep<2048, 11><<<nblk, 512, 0, stream>>>(enc, gamma, w, bias, out);
    } else {
        lo_kernel_generic<<<n_rows, 256, 0, stream>>>(enc, gamma, w, bias, out,
                                                      N_IMG, S, D);
    }
}

// Round 6
// 15.726 us; speedup vs baseline: 1.5355x; 1.1301x over previous
//
#include <hip/hip_runtime.h>

#define EPS 1e-6f

using f4 = __attribute__((ext_vector_type(4))) float;

// Best-measured variant (R3, 15.69 us): fused RMSNorm + weighted-dot,
// wave-per-2-rows. gamma*w precomputed into 32 VGPRs per wave; hot loop
// reads ONLY x (8x global_load_dwordx4 nt per row), 4 independent FMA
// chains via vector accumulators. 1024 blocks x 256 thr = 4 blocks/CU,
// 16 waves/CU — occupancy proven NOT the limiter (R4), access order
// proven not the limiter (R5); remaining gap to the 10.6 us HBM floor
// is fixed dispatch overhead.
template<int D, int R>
__global__ __launch_bounds__(256, 4) void lo_kernel(
    const float* __restrict__ enc,
    const float* __restrict__ gamma,
    const float* __restrict__ w,
    const float* __restrict__ bias,
    float* __restrict__ out,
    int N_IMG, int S, int n_rows)
{
    constexpr int ITER = D / 256;           // 64 lanes * 4 floats
    const int lane = threadIdx.x & 63;
    const int wid  = threadIdx.x >> 6;
    const int wave = blockIdx.x * 4 + wid;
    const int row0 = wave * R;
    if (row0 >= n_rows) return;

    const int col = lane * 4;

    // gamma*w -> registers, once per wave (L2-resident reads)
    f4 gw[ITER];
    #pragma unroll
    for (int i = 0; i < ITER; ++i) {
        const int idx = i * 256 + col;
        const f4 gv = *reinterpret_cast<const f4*>(gamma + idx);
        const f4 wv = *reinterpret_cast<const f4*>(w + idx);
        gw[i] = gv * wv;
    }

    const float bb = bias[0];

    #pragma unroll
    for (int r = 0; r < R; ++r) {
        const int row = row0 + r;
        if (row >= n_rows) break;
        const int b = row / N_IMG;
        const int n = row - b * N_IMG;
        const float* __restrict__ x = enc + ((size_t)b * S + n) * (size_t)D;

        f4 sq = {0.f, 0.f, 0.f, 0.f};
        f4 dt = {0.f, 0.f, 0.f, 0.f};
        #pragma unroll
        for (int i = 0; i < ITER; ++i) {
            const f4 xv = __builtin_nontemporal_load(
                reinterpret_cast<const f4*>(x + i * 256 + col));
            sq += xv * xv;
            dt += xv * gw[i];
        }

        float ssq = sq.x + sq.y + sq.z + sq.w;
        float ddt = dt.x + dt.y + dt.z + dt.w;
        #pragma unroll
        for (int o = 32; o > 0; o >>= 1) {
            ssq += __shfl_xor(ssq, o, 64);
            ddt += __shfl_xor(ddt, o, 64);
        }
        if (lane == 0) {
            out[row] = ddt * rsqrtf(ssq * (1.0f / (float)D) + EPS) + bb;
        }
    }
}

// Generic fallback (runtime D), block-per-row.
__global__ __launch_bounds__(256) void lo_kernel_generic(
    const float* __restrict__ enc,
    const float* __restrict__ gamma,
    const float* __restrict__ w,
    const float* __restrict__ bias,
    float* __restrict__ out,
    int N_IMG, int S, int D)
{
    const int row = blockIdx.x;
    const int b   = row / N_IMG;
    const int n   = row % N_IMG;
    const float* __restrict__ x = enc + ((size_t)b * S + n) * (size_t)D;
    const int t = threadIdx.x;

    float sumsq = 0.f, dot = 0.f;
    for (int d = t; d < D; d += 256) {
        const float xv = x[d];
        sumsq = fmaf(xv, xv, sumsq);
        dot   = fmaf(xv * gamma[d], w[d], dot);
    }
    #pragma unroll
    for (int o = 32; o > 0; o >>= 1) {
        sumsq += __shfl_xor(sumsq, o, 64);
        dot   += __shfl_xor(dot,   o, 64);
    }
    __shared__ float s_sq[4], s_dot[4];
    const int wid = t >> 6, lane = t & 63;
    if (lane == 0) { s_sq[wid] = sumsq; s_dot[wid] = dot; }
    __syncthreads();
    if (t == 0) {
        float ss = s_sq[0] + s_sq[1] + s_sq[2] + s_sq[3];
        float dd = s_dot[0] + s_dot[1] + s_dot[2] + s_dot[3];
        out[row] = dd * rsqrtf(ss / (float)D + EPS) + bias[0];
    }
}

extern "C" void kernel_launch(void* const* d_in, const int* in_sizes, int n_in,
                              void* d_out, int out_size, void* d_ws, size_t ws_size,
                              hipStream_t stream) {
    const float* enc   = (const float*)d_in[0];   // (B, S, D)
    const float* gamma = (const float*)d_in[3];   // (D,)
    const float* w     = (const float*)d_in[4];   // (D,)
    const float* bias  = (const float*)d_in[5];   // scalar
    float* out         = (float*)d_out;           // (B, N_IMG)

    const int D      = in_sizes[3];               // 2048
    const int B      = 4;
    const int BN     = in_sizes[1];               // B * N_IMG
    const int N_IMG  = BN / B;
    const int S      = in_sizes[0] / (B * D);
    const int n_rows = out_size;                  // B * N_IMG

    if (D == 2048) {
        constexpr int R = 2;
        const int waves  = (n_rows + R - 1) / R;  // 4096
        const int blocks = (waves + 3) / 4;       // 1024
        lo_kernel<2048, R><<<blocks, 256, 0, stream>>>(enc, gamma, w, bias, out,
                                                       N_IMG, S, n_rows);
    } else {
        lo_kernel_generic<<<n_rows, 256, 0, stream>>>(enc, gamma, w, bias, out,
                                                      N_IMG, S, D);
    }
}